// Round 1
// baseline (784.067 us; speedup 1.0000x reference)
//
#include <hip/hip_runtime.h>
#include <hip/hip_bf16.h>

// Round 1: full fused MoE pipeline, bf16 MFMA experts + split-bf16 fp32-accurate gate.
#define N_TOK 16384

typedef __attribute__((ext_vector_type(8))) short bf16x8;
typedef __attribute__((ext_vector_type(4))) float f32x4;
typedef unsigned short u16;

__device__ __forceinline__ u16 f2bf(float f) {
  __hip_bfloat16 h = __float2bfloat16(f);
  union { __hip_bfloat16 b; u16 u; } c; c.b = h; return c.u;
}
__device__ __forceinline__ float bfbits2f(u16 u) {
  return __uint_as_float(((unsigned)u) << 16);
}
__device__ __forceinline__ float gelu_erf(float x) {
  return 0.5f * x * (1.0f + erff(x * 0.70710678118654752f));
}
#define SWZ(b, r) ((b) ^ (((r) & 7) << 4))

// ---------------------------------------------------------------------------
// prep kernels
// ---------------------------------------------------------------------------
__global__ __launch_bounds__(256) void prep_x(const float* __restrict__ x,
                                              u16* __restrict__ xbf,
                                              u16* __restrict__ xlo) {
  size_t i = (size_t)blockIdx.x * 256 + threadIdx.x;  // group of 4 floats
  float4 v = ((const float4*)x)[i];
  float a[4] = {v.x, v.y, v.z, v.w};
  union { u16 us[4]; unsigned long long ll; } hb, lb;
#pragma unroll
  for (int j = 0; j < 4; ++j) {
    u16 hu = f2bf(a[j]);
    hb.us[j] = hu;
    lb.us[j] = f2bf(a[j] - bfbits2f(hu));
  }
  *(unsigned long long*)(xbf + i * 4) = hb.ll;
  *(unsigned long long*)(xlo + i * 4) = lb.ll;
}

// dst[e][c][r] = bf16(src[e][r][c])   (grid covers E*R*C exactly)
__global__ __launch_bounds__(256) void transpose_bf(const float* __restrict__ src,
                                                    u16* __restrict__ dst,
                                                    int R, int C) {
  size_t i = (size_t)blockIdx.x * 256 + threadIdx.x;
  size_t rc = (size_t)R * C;
  size_t e = i / rc, rem = i % rc;
  size_t c = rem / R, r = rem % R;
  dst[i] = f2bf(src[e * rc + r * C + c]);
}

// wcat[n*1536+k]: k<512 -> hi(W[k][n]); k<1024 -> lo(W[k-512][n]); else hi(W[k-1024][n])
__global__ __launch_bounds__(256) void prep_wcat(const float* __restrict__ gw1,
                                                 u16* __restrict__ wcat) {
  int i = blockIdx.x * 256 + threadIdx.x;
  int n = i / 1536, k = i % 1536;
  u16 o;
  if (k < 512) {
    o = f2bf(gw1[k * 512 + n]);
  } else if (k < 1024) {
    float w = gw1[(k - 512) * 512 + n];
    o = f2bf(w - bfbits2f(f2bf(w)));
  } else {
    o = f2bf(gw1[(k - 1024) * 512 + n]);
  }
  wcat[i] = o;
}

// w2t[e][k] = g_w2[k][e]  (fp32, 8x512)
__global__ __launch_bounds__(256) void prep_w2t(const float* __restrict__ gw2,
                                                float* __restrict__ w2t) {
  int i = blockIdx.x * 256 + threadIdx.x;
  int e = i >> 9, k = i & 511;
  w2t[i] = gw2[k * 8 + e];
}

// ---------------------------------------------------------------------------
// main GEMM: out = gelu(LN(A @ W + bias))   BM=64, BN=512(full), BK=64, 8 waves
// A: [M][512] bf16 (row-major); Wt: [512 n][K k] bf16 (pre-transposed)
// K=1536 selects split segments of A (hi,hi,lo) for the fp32-accurate gate.
// ---------------------------------------------------------------------------
__global__ __launch_bounds__(512) void gemm_ln_gelu(
    const u16* __restrict__ A, const u16* __restrict__ A2, long a_estride,
    const u16* __restrict__ Wt, long w_estride,
    const float* __restrict__ bias, int b_estride,
    const float* __restrict__ lng, const float* __restrict__ lnb,
    u16* __restrict__ outb, float* __restrict__ outf, long o_estride, int K) {
  extern __shared__ char smem[];
  char* smA = smem;                              // 64*128B  = 8192
  char* smB = smem + 8192;                       // 512*128B = 65536
  float* red = (float*)(smem + 8192 + 65536);    // 64*8 f32 = 2048

  const int tid = threadIdx.x;
  const int lane = tid & 63;
  const int wv = tid >> 6;
  const int wm = (wv >> 2) * 32;   // 0,32
  const int wn = (wv & 3) * 128;   // 0..384
  const int l15 = lane & 15;
  const int lk = lane >> 4;
  const int e = blockIdx.y;
  const int rbase = blockIdx.x * 64;

  const u16* Ae = A + (size_t)e * a_estride;
  const u16* We = Wt + (size_t)e * w_estride;
  const float* be = bias + (size_t)e * b_estride;
  const float* ge = lng + (size_t)e * b_estride;
  const float* bbe = lnb + (size_t)e * b_estride;

  f32x4 acc[2][8];
#pragma unroll
  for (int i = 0; i < 2; ++i)
#pragma unroll
    for (int j = 0; j < 8; ++j) acc[i][j] = (f32x4){0.f, 0.f, 0.f, 0.f};

  const int ar = tid >> 3, ac = tid & 7;  // A staging: row, 16B chunk
  const int bn = tid;                     // B staging: row n

  for (int k0 = 0; k0 < K; k0 += 64) {
    const u16* Aseg; int kc;
    if (k0 < 512)       { Aseg = Ae; kc = k0; }
    else if (k0 < 1024) { Aseg = Ae; kc = k0 - 512; }
    else                { Aseg = A2; kc = k0 - 1024; }

    __syncthreads();
    bf16x8 av = *(const bf16x8*)(Aseg + (size_t)(rbase + ar) * 512 + kc + ac * 8);
    *(bf16x8*)(smA + SWZ(ar * 128 + ac * 16, ar)) = av;
    const u16* bp = We + (size_t)bn * K + k0;
#pragma unroll
    for (int c = 0; c < 8; ++c) {
      bf16x8 bv = *(const bf16x8*)(bp + c * 8);
      *(bf16x8*)(smB + SWZ(bn * 128 + c * 16, bn)) = bv;
    }
    __syncthreads();

#pragma unroll
    for (int s = 0; s < 2; ++s) {
      bf16x8 af[2], bfr[8];
#pragma unroll
      for (int fm = 0; fm < 2; ++fm) {
        int r = wm + fm * 16 + l15;
        af[fm] = *(const bf16x8*)(smA + SWZ(r * 128 + s * 64 + lk * 16, r));
      }
#pragma unroll
      for (int fn = 0; fn < 8; ++fn) {
        int n = wn + fn * 16 + l15;
        bfr[fn] = *(const bf16x8*)(smB + SWZ(n * 128 + s * 64 + lk * 16, n));
      }
#pragma unroll
      for (int fm = 0; fm < 2; ++fm)
#pragma unroll
        for (int fn = 0; fn < 8; ++fn)
          acc[fm][fn] = __builtin_amdgcn_mfma_f32_16x16x32_bf16(
              af[fm], bfr[fn], acc[fm][fn], 0, 0, 0);
    }
  }

  // ---- epilogue: +bias, LN over full 512 row, GELU(erf), store ----
  float bias_v[8], g_v[8], b_v[8];
#pragma unroll
  for (int fn = 0; fn < 8; ++fn) {
    int col = wn + fn * 16 + l15;
    bias_v[fn] = be[col]; g_v[fn] = ge[col]; b_v[fn] = bbe[col];
  }
#pragma unroll
  for (int fm = 0; fm < 2; ++fm)
#pragma unroll
    for (int fn = 0; fn < 8; ++fn)
#pragma unroll
      for (int r = 0; r < 4; ++r) acc[fm][fn][r] += bias_v[fn];

  float s1[2][4], s2[2][4];
#pragma unroll
  for (int fm = 0; fm < 2; ++fm)
#pragma unroll
    for (int r = 0; r < 4; ++r) {
      float a1 = 0.f, a2 = 0.f;
#pragma unroll
      for (int fn = 0; fn < 8; ++fn) {
        float v = acc[fm][fn][r];
        a1 += v; a2 += v * v;
      }
#pragma unroll
      for (int m = 1; m < 16; m <<= 1) {  // reduce over the 16 lanes sharing rows
        a1 += __shfl_xor(a1, m, 64);
        a2 += __shfl_xor(a2, m, 64);
      }
      s1[fm][r] = a1; s2[fm][r] = a2;
    }
  if (l15 == 0) {
#pragma unroll
    for (int fm = 0; fm < 2; ++fm)
#pragma unroll
      for (int r = 0; r < 4; ++r) {
        int row = wm + fm * 16 + lk * 4 + r;
        red[row * 8 + (wv & 3) * 2] = s1[fm][r];
        red[row * 8 + (wv & 3) * 2 + 1] = s2[fm][r];
      }
  }
  __syncthreads();
#pragma unroll
  for (int fm = 0; fm < 2; ++fm)
#pragma unroll
    for (int r = 0; r < 4; ++r) {
      int row = wm + fm * 16 + lk * 4 + r;
      float S1 = red[row * 8] + red[row * 8 + 2] + red[row * 8 + 4] + red[row * 8 + 6];
      float S2 = red[row * 8 + 1] + red[row * 8 + 3] + red[row * 8 + 5] + red[row * 8 + 7];
      float mu = S1 * (1.0f / 512.0f);
      float var = S2 * (1.0f / 512.0f) - mu * mu;
      float rs = rsqrtf(var + 1e-5f);
      size_t rowg = (size_t)(rbase + row);
#pragma unroll
      for (int fn = 0; fn < 8; ++fn) {
        int col = wn + fn * 16 + l15;
        float v = (acc[fm][fn][r] - mu) * rs * g_v[fn] + b_v[fn];
        v = gelu_erf(v);
        if (outf) outf[rowg * 512 + col] = v;
        else      outb[(size_t)e * o_estride + rowg * 512 + col] = f2bf(v);
      }
    }
}

// ---------------------------------------------------------------------------
// gate GEMM2 (fp32) + softmax + top-2 + w_dense.  One wave per token.
// ---------------------------------------------------------------------------
__global__ __launch_bounds__(256) void gate2_topk(
    const float* __restrict__ gh, const float* __restrict__ w2t,
    const float* __restrict__ b2, float* __restrict__ gwout,
    float* __restrict__ idxout, float* __restrict__ tkwout,
    float* __restrict__ wdense) {
  const int lane = threadIdx.x & 63;
  const int wv = threadIdx.x >> 6;
  const int t = blockIdx.x * 4 + wv;
  const float4* xr = (const float4*)(gh + (size_t)t * 512);
  float4 x0 = xr[lane * 2], x1 = xr[lane * 2 + 1];
  float logit[8];
#pragma unroll
  for (int e = 0; e < 8; ++e) {
    const float4* wr = (const float4*)(w2t + e * 512);
    float4 w0 = wr[lane * 2], w1 = wr[lane * 2 + 1];
    float p = x0.x * w0.x + x0.y * w0.y + x0.z * w0.z + x0.w * w0.w +
              x1.x * w1.x + x1.y * w1.y + x1.z * w1.z + x1.w * w1.w;
#pragma unroll
    for (int m = 1; m < 64; m <<= 1) p += __shfl_xor(p, m, 64);
    logit[e] = p + b2[e];
  }
  if (lane == 0) {
    float mx = logit[0];
#pragma unroll
    for (int e = 1; e < 8; ++e) mx = fmaxf(mx, logit[e]);
    float w[8], ssum = 0.f;
#pragma unroll
    for (int e = 0; e < 8; ++e) { w[e] = expf(logit[e] - mx); ssum += w[e]; }
    float inv = 1.0f / ssum;
#pragma unroll
    for (int e = 0; e < 8; ++e) w[e] *= inv;
    float w1v = -1.f, w2v = -1.f; int i1 = 0, i2 = 0;
#pragma unroll
    for (int e = 0; e < 8; ++e) {
      float v = w[e];
      if (v > w1v)      { w2v = w1v; i2 = i1; w1v = v; i1 = e; }
      else if (v > w2v) { w2v = v; i2 = e; }
    }
    float s = w1v + w2v;
    float t1 = w1v / s, t2 = w2v / s;
#pragma unroll
    for (int e = 0; e < 8; ++e) gwout[t * 8 + e] = w[e];
    idxout[t * 2] = (float)i1; idxout[t * 2 + 1] = (float)i2;
    tkwout[t * 2] = t1;        tkwout[t * 2 + 1] = t2;
#pragma unroll
    for (int e = 0; e < 8; ++e)
      wdense[t * 8 + e] = (e == i1) ? t1 : ((e == i2) ? t2 : 0.0f);
  }
}

__global__ __launch_bounds__(256) void usage_k(const float* __restrict__ gw,
                                               float* __restrict__ usage) {
  __shared__ float r[256];
  int e = blockIdx.x;
  float s = 0.f;
  for (int t = threadIdx.x; t < N_TOK; t += 256) s += gw[t * 8 + e];
  r[threadIdx.x] = s;
  __syncthreads();
  for (int st = 128; st > 0; st >>= 1) {
    if (threadIdx.x < st) r[threadIdx.x] += r[threadIdx.x + st];
    __syncthreads();
  }
  if (threadIdx.x == 0) usage[e] = r[0] * (1.0f / (float)N_TOK);
}

// ---------------------------------------------------------------------------
// expert GEMM3 (h2 @ w3 + b3), weighted combine over experts, + final proj.
// BM=64 tokens x 64 outs, 4 waves. comb accumulated in registers across e.
// ---------------------------------------------------------------------------
__global__ __launch_bounds__(256) void gemm3_proj(
    const u16* __restrict__ h, const u16* __restrict__ w3t,
    const float* __restrict__ b3, const float* __restrict__ wdense,
    const float* __restrict__ pw, const float* __restrict__ pb,
    float* __restrict__ outp) {
  __shared__ u16 As[64 * 64];
  __shared__ u16 Bs[64 * 64];
  __shared__ float combs[64 * 65];
  __shared__ float pws[64 * 65];

  const int tid = threadIdx.x;
  const int lane = tid & 63;
  const int wq = tid >> 6;
  const int l15 = lane & 15, lk = lane >> 4;
  const int rbase = blockIdx.x * 64;

  {
    int c = tid >> 2, og = (tid & 3) * 16;
#pragma unroll
    for (int i = 0; i < 16; ++i) pws[c * 65 + og + i] = pw[c * 64 + og + i];
  }

  f32x4 comb[4];
#pragma unroll
  for (int fn = 0; fn < 4; ++fn) comb[fn] = (f32x4){0.f, 0.f, 0.f, 0.f};

  for (int e = 0; e < 8; ++e) {
    f32x4 acc[4];
#pragma unroll
    for (int fn = 0; fn < 4; ++fn) acc[fn] = (f32x4){0.f, 0.f, 0.f, 0.f};
    const u16* he = h + (size_t)e * N_TOK * 512;
    const u16* we = w3t + (size_t)e * 64 * 512;
    for (int k0 = 0; k0 < 512; k0 += 64) {
      __syncthreads();
#pragma unroll
      for (int rep = 0; rep < 2; ++rep) {
        int idx = tid + rep * 256;
        int row = idx >> 3, c = idx & 7;
        bf16x8 av = *(const bf16x8*)(he + (size_t)(rbase + row) * 512 + k0 + c * 8);
        *(bf16x8*)((char*)As + SWZ(row * 128 + c * 16, row)) = av;
        bf16x8 wv = *(const bf16x8*)(we + (size_t)row * 512 + k0 + c * 8);
        *(bf16x8*)((char*)Bs + SWZ(row * 128 + c * 16, row)) = wv;
      }
      __syncthreads();
#pragma unroll
      for (int s = 0; s < 2; ++s) {
        int r = wq * 16 + l15;
        bf16x8 a = *(const bf16x8*)((char*)As + SWZ(r * 128 + s * 64 + lk * 16, r));
#pragma unroll
        for (int fn = 0; fn < 4; ++fn) {
          int n = fn * 16 + l15;
          bf16x8 b = *(const bf16x8*)((char*)Bs + SWZ(n * 128 + s * 64 + lk * 16, n));
          acc[fn] = __builtin_amdgcn_mfma_f32_16x16x32_bf16(a, b, acc[fn], 0, 0, 0);
        }
      }
    }
    float b3v[4];
#pragma unroll
    for (int fn = 0; fn < 4; ++fn) b3v[fn] = b3[e * 64 + fn * 16 + l15];
#pragma unroll
    for (int r = 0; r < 4; ++r) {
      float wgt = wdense[(size_t)(rbase + wq * 16 + lk * 4 + r) * 8 + e];
#pragma unroll
      for (int fn = 0; fn < 4; ++fn) comb[fn][r] += wgt * (acc[fn][r] + b3v[fn]);
    }
  }
#pragma unroll
  for (int fn = 0; fn < 4; ++fn)
#pragma unroll
    for (int r = 0; r < 4; ++r)
      combs[(wq * 16 + lk * 4 + r) * 65 + fn * 16 + l15] = comb[fn][r];
  __syncthreads();
  {
    int t = tid >> 2, og = (tid & 3) * 16;
    float sums[16];
#pragma unroll
    for (int i = 0; i < 16; ++i) sums[i] = 0.f;
    for (int c = 0; c < 64; ++c) {
      float cv = combs[t * 65 + c];
#pragma unroll
      for (int i = 0; i < 16; ++i) sums[i] += cv * pws[c * 65 + og + i];
    }
#pragma unroll
    for (int i = 0; i < 16; ++i)
      outp[(size_t)(rbase + t) * 64 + og + i] = sums[i] + pb[og + i];
  }
}

// ---------------------------------------------------------------------------
extern "C" void kernel_launch(void* const* d_in, const int* in_sizes, int n_in,
                              void* d_out, int out_size, void* d_ws, size_t ws_size,
                              hipStream_t stream) {
  const float* x      = (const float*)d_in[0];
  const float* g_w1   = (const float*)d_in[1];
  const float* g_b1   = (const float*)d_in[2];
  const float* g_lng  = (const float*)d_in[3];
  const float* g_lnb  = (const float*)d_in[4];
  const float* g_w2   = (const float*)d_in[5];
  const float* g_b2   = (const float*)d_in[6];
  const float* e_w1   = (const float*)d_in[7];
  const float* e_b1   = (const float*)d_in[8];
  const float* e_ln1g = (const float*)d_in[9];
  const float* e_ln1b = (const float*)d_in[10];
  const float* e_w2   = (const float*)d_in[11];
  const float* e_b2   = (const float*)d_in[12];
  const float* e_ln2g = (const float*)d_in[13];
  const float* e_ln2b = (const float*)d_in[14];
  const float* e_w3   = (const float*)d_in[15];
  const float* e_b3   = (const float*)d_in[16];
  const float* p_w    = (const float*)d_in[17];
  const float* p_b    = (const float*)d_in[18];

  char* ws = (char*)d_ws;
  u16*   x_bf  = (u16*)(ws);                     // 16 MB
  u16*   e_w1t = (u16*)(ws + (16ull << 20));     // 4 MB
  u16*   e_w2t = (u16*)(ws + (20ull << 20));     // 4 MB
  u16*   e_w3t = (u16*)(ws + (24ull << 20));     // 0.5 MB
  u16*   wcat  = (u16*)(ws + (25ull << 20));     // 1.5 MB
  float* w2t   = (float*)(ws + (27ull << 20));   // 16 KB
  float* wdns  = (float*)(ws + (28ull << 20));   // 512 KB
  // overlay region @29MB: [gh 32MB][x_lo 16MB] then h (128MB) reuses it after gate done
  float* gh    = (float*)(ws + (29ull << 20));
  u16*   x_lo  = (u16*)(ws + (61ull << 20));
  u16*   h     = (u16*)(ws + (29ull << 20));
  // total need: 157 MB
  if (ws_size < (157ull << 20)) return;  // clean wrong-answer fail (diagnosable)

  float* fout = (float*)d_out;
  float* o_output = fout;                 // 16384*64
  float* o_gatew  = fout + 1048576;       // 16384*8
  float* o_idx    = fout + 1179648;       // 16384*2
  float* o_topw   = fout + 1212416;       // 16384*2
  float* o_usage  = fout + 1245184;       // 8

  (void)hipFuncSetAttribute((const void*)gemm_ln_gelu,
                            hipFuncAttributeMaxDynamicSharedMemorySize, 75776);

  prep_x<<<8192, 256, 0, stream>>>(x, x_bf, x_lo);
  transpose_bf<<<8192, 256, 0, stream>>>(e_w1, e_w1t, 512, 512);
  transpose_bf<<<8192, 256, 0, stream>>>(e_w2, e_w2t, 512, 512);
  transpose_bf<<<1024, 256, 0, stream>>>(e_w3, e_w3t, 512, 64);
  prep_wcat<<<3072, 256, 0, stream>>>(g_w1, wcat);
  prep_w2t<<<16, 256, 0, stream>>>(g_w2, w2t);

  // gate GEMM (split-bf16, K=1536, fp32-accurate) -> gh (fp32)
  dim3 g1(256, 1);
  gemm_ln_gelu<<<g1, 512, 75776, stream>>>(x_bf, x_lo, 0, wcat, 0, g_b1, 0,
                                           g_lng, g_lnb, nullptr, gh, 0, 1536);
  gate2_topk<<<4096, 256, 0, stream>>>(gh, w2t, g_b2, o_gatew, o_idx, o_topw, wdns);
  usage_k<<<8, 256, 0, stream>>>(o_gatew, o_usage);

  // experts: L1 (x -> h), L2 (h -> h, in-place safe: wg reads only its own rows)
  dim3 g8(256, 8);
  gemm_ln_gelu<<<g8, 512, 75776, stream>>>(x_bf, nullptr, 0, e_w1t, 512 * 512,
                                           e_b1, 512, e_ln1g, e_ln1b, h, nullptr,
                                           (long)N_TOK * 512, 512);
  gemm_ln_gelu<<<g8, 512, 75776, stream>>>(h, nullptr, (long)N_TOK * 512, e_w2t,
                                           512 * 512, e_b2, 512, e_ln2g, e_ln2b,
                                           h, nullptr, (long)N_TOK * 512, 512);
  gemm3_proj<<<256, 256, 0, stream>>>(h, e_w3t, e_b3, wdns, p_w, p_b, o_output);
}

// Round 2
// 603.686 us; speedup vs baseline: 1.2988x; 1.2988x over previous
//
#include <hip/hip_runtime.h>
#include <hip/hip_bf16.h>

// Round 2: global_load_lds staging (pre-swizzled source), BM=128 / 16-wave /
// 64x64-per-wave tiles, tiled weight transposes.
#define N_TOK 16384

typedef __attribute__((ext_vector_type(8))) short bf16x8;
typedef __attribute__((ext_vector_type(4))) float f32x4;
typedef unsigned short u16;

__device__ __forceinline__ u16 f2bf(float f) {
  __hip_bfloat16 h = __float2bfloat16(f);
  union { __hip_bfloat16 b; u16 u; } c; c.b = h; return c.u;
}
__device__ __forceinline__ float bfbits2f(u16 u) {
  return __uint_as_float(((unsigned)u) << 16);
}
__device__ __forceinline__ float gelu_erf(float x) {
  return 0.5f * x * (1.0f + erff(x * 0.70710678118654752f));
}
#define SWZ(b, r) ((b) ^ (((r) & 7) << 4))

__device__ __forceinline__ void gload16(const u16* g, char* lds) {
  __builtin_amdgcn_global_load_lds(
      (const __attribute__((address_space(1))) void*)g,
      (__attribute__((address_space(3))) void*)lds, 16, 0, 0);
}

// ---------------------------------------------------------------------------
// prep kernels
// ---------------------------------------------------------------------------
__global__ __launch_bounds__(256) void prep_x(const float* __restrict__ x,
                                              u16* __restrict__ xbf,
                                              u16* __restrict__ xlo) {
  size_t i = (size_t)blockIdx.x * 256 + threadIdx.x;
  float4 v = ((const float4*)x)[i];
  float a[4] = {v.x, v.y, v.z, v.w};
  union { u16 us[4]; unsigned long long ll; } hb, lb;
#pragma unroll
  for (int j = 0; j < 4; ++j) {
    u16 hu = f2bf(a[j]);
    hb.us[j] = hu;
    lb.us[j] = f2bf(a[j] - bfbits2f(hu));
  }
  *(unsigned long long*)(xbf + i * 4) = hb.ll;
  *(unsigned long long*)(xlo + i * 4) = lb.ll;
}

// dst[e][c][r] = bf16(src[e][r][c]) via 64x64 LDS tile
__global__ __launch_bounds__(256) void transpose_bf_tiled(
    const float* __restrict__ src, u16* __restrict__ dst, int R, int C) {
  __shared__ float t[64][65];
  const int e = blockIdx.z;
  const int r0 = blockIdx.x * 64, c0 = blockIdx.y * 64;
  const float* s = src + (size_t)e * R * C;
  const int tr = threadIdx.x >> 2;
  const int tc4 = (threadIdx.x & 3) * 16;
#pragma unroll
  for (int j = 0; j < 4; ++j) {
    float4 v = *(const float4*)(s + (size_t)(r0 + tr) * C + c0 + tc4 + j * 4);
    t[tr][tc4 + j * 4 + 0] = v.x;
    t[tr][tc4 + j * 4 + 1] = v.y;
    t[tr][tc4 + j * 4 + 2] = v.z;
    t[tr][tc4 + j * 4 + 3] = v.w;
  }
  __syncthreads();
  const int oc = threadIdx.x >> 2;  // out row (= src col within tile)
  union { u16 us[16]; unsigned long long ll[4]; } o;
#pragma unroll
  for (int j = 0; j < 16; ++j) o.us[j] = f2bf(t[tc4 + j][oc]);
  unsigned long long* d =
      (unsigned long long*)(dst + (size_t)e * R * C + (size_t)(c0 + oc) * R + r0 + tc4);
#pragma unroll
  for (int j = 0; j < 4; ++j) d[j] = o.ll[j];
}

// wcat[n*1536+k]: k<512 -> hi(W[k][n]); k<1024 -> lo(W[k-512][n]); else hi(W[k-1024][n])
__global__ __launch_bounds__(256) void prep_wcat(const float* __restrict__ gw1,
                                                 u16* __restrict__ wcat) {
  int i = blockIdx.x * 256 + threadIdx.x;
  int n = i / 1536, k = i % 1536;
  u16 o;
  if (k < 512) {
    o = f2bf(gw1[k * 512 + n]);
  } else if (k < 1024) {
    float w = gw1[(k - 512) * 512 + n];
    o = f2bf(w - bfbits2f(f2bf(w)));
  } else {
    o = f2bf(gw1[(k - 1024) * 512 + n]);
  }
  wcat[i] = o;
}

__global__ __launch_bounds__(256) void prep_w2t(const float* __restrict__ gw2,
                                                float* __restrict__ w2t) {
  int i = blockIdx.x * 256 + threadIdx.x;
  int e = i >> 9, k = i & 511;
  w2t[i] = gw2[k * 8 + e];
}

// ---------------------------------------------------------------------------
// main GEMM: out = gelu(LN(A @ W + bias))
// BM=128, BN=512(full row for LN), BK=64, 1024 threads (16 waves, 64x64/wave)
// Staging: global_load_lds w=16, source chunk pre-swizzled (c ^ (row&7)),
// LDS linear; reads apply SWZ. K=1536 variant = split-bf16 fp32-accurate gate.
// ---------------------------------------------------------------------------
__global__ __launch_bounds__(1024, 4) void gemm_ln_gelu(
    const u16* __restrict__ A, const u16* __restrict__ A2, long a_estride,
    const u16* __restrict__ Wt, long w_estride,
    const float* __restrict__ bias, int b_estride,
    const float* __restrict__ lng, const float* __restrict__ lnb,
    u16* __restrict__ outb, float* __restrict__ outf, long o_estride, int K) {
  extern __shared__ char smem[];
  char* smA = smem;           // 128*128B = 16384
  char* smB = smem + 16384;   // 512*128B = 65536

  const int tid = threadIdx.x;
  const int lane = tid & 63;
  const int wv = tid >> 6;          // 0..15
  const int wm = (wv & 1) * 64;     // wave m-origin (4 frags)
  const int wn = (wv >> 1) * 64;    // wave n-origin (4 frags)
  const int l15 = lane & 15;
  const int lk = lane >> 4;
  const int e = blockIdx.y;
  const int rbase = blockIdx.x * 128;

  const u16* Ae = A + (size_t)e * a_estride;
  const u16* We = Wt + (size_t)e * w_estride;

  // staging geometry: 80 wave-loads/k-step (A:16, B:64), 5 per wave
  const int row_off = lane >> 3;        // 0..7
  const int cs = (lane & 7) ^ row_off;  // pre-swizzled chunk

  f32x4 acc[4][4];
#pragma unroll
  for (int i = 0; i < 4; ++i)
#pragma unroll
    for (int j = 0; j < 4; ++j) acc[i][j] = (f32x4){0.f, 0.f, 0.f, 0.f};

  for (int k0 = 0; k0 < K; k0 += 64) {
    const u16* Aseg; int kc;
    if (k0 < 512)       { Aseg = Ae; kc = k0; }
    else if (k0 < 1024) { Aseg = Ae; kc = k0 - 512; }   // hi * w_lo
    else                { Aseg = A2; kc = k0 - 1024; }  // lo * w_hi

    __syncthreads();
#pragma unroll
    for (int i = 0; i < 5; ++i) {
      int id = wv * 5 + i;
      if (id < 16) {
        int br = id * 8;
        const u16* src = Aseg + (size_t)(rbase + br + row_off) * 512 + kc + cs * 8;
        gload16(src, smA + br * 128);
      } else {
        int br = (id - 16) * 8;
        const u16* src = We + (size_t)(br + row_off) * K + k0 + cs * 8;
        gload16(src, smB + br * 128);
      }
    }
    __syncthreads();

#pragma unroll
    for (int s = 0; s < 2; ++s) {
      bf16x8 af[4];
#pragma unroll
      for (int fm = 0; fm < 4; ++fm) {
        int r = wm + fm * 16 + l15;
        af[fm] = *(const bf16x8*)(smA + SWZ(r * 128 + s * 64 + lk * 16, r));
      }
#pragma unroll
      for (int fn = 0; fn < 4; ++fn) {
        int n = wn + fn * 16 + l15;
        bf16x8 bv = *(const bf16x8*)(smB + SWZ(n * 128 + s * 64 + lk * 16, n));
#pragma unroll
        for (int fm = 0; fm < 4; ++fm)
          acc[fm][fn] = __builtin_amdgcn_mfma_f32_16x16x32_bf16(
              af[fm], bv, acc[fm][fn], 0, 0, 0);
      }
    }
  }

  // ---- epilogue: +bias, LN over 512 row, GELU(erf), store ----
  const float* be = bias + (size_t)e * b_estride;
  const float* ge = lng + (size_t)e * b_estride;
  const float* bbe = lnb + (size_t)e * b_estride;
  float bias_v[4], g_v[4], b_v[4];
#pragma unroll
  for (int fn = 0; fn < 4; ++fn) {
    int col = wn + fn * 16 + l15;
    bias_v[fn] = be[col]; g_v[fn] = ge[col]; b_v[fn] = bbe[col];
  }
#pragma unroll
  for (int fm = 0; fm < 4; ++fm)
#pragma unroll
    for (int fn = 0; fn < 4; ++fn)
#pragma unroll
      for (int r = 0; r < 4; ++r) acc[fm][fn][r] += bias_v[fn];

  __syncthreads();                 // smA reads complete before aliasing
  float* red = (float*)smem;       // [row 0..127][g 0..7][2] = 8 KB
  const int g = wv >> 1;
#pragma unroll
  for (int fm = 0; fm < 4; ++fm)
#pragma unroll
    for (int r = 0; r < 4; ++r) {
      float a1 = 0.f, a2 = 0.f;
#pragma unroll
      for (int fn = 0; fn < 4; ++fn) {
        float v = acc[fm][fn][r];
        a1 += v; a2 += v * v;
      }
#pragma unroll
      for (int m = 1; m < 16; m <<= 1) {
        a1 += __shfl_xor(a1, m, 64);
        a2 += __shfl_xor(a2, m, 64);
      }
      if (l15 == 0) {
        int row = wm + fm * 16 + lk * 4 + r;
        red[(row * 8 + g) * 2] = a1;
        red[(row * 8 + g) * 2 + 1] = a2;
      }
    }
  __syncthreads();
#pragma unroll
  for (int fm = 0; fm < 4; ++fm)
#pragma unroll
    for (int r = 0; r < 4; ++r) {
      int row = wm + fm * 16 + lk * 4 + r;
      float S1 = 0.f, S2 = 0.f;
#pragma unroll
      for (int q = 0; q < 8; ++q) {
        S1 += red[(row * 8 + q) * 2];
        S2 += red[(row * 8 + q) * 2 + 1];
      }
      float mu = S1 * (1.0f / 512.0f);
      float var = S2 * (1.0f / 512.0f) - mu * mu;
      float rs = rsqrtf(var + 1e-5f);
      size_t rowg = (size_t)(rbase + row);
#pragma unroll
      for (int fn = 0; fn < 4; ++fn) {
        int col = wn + fn * 16 + l15;
        float v = (acc[fm][fn][r] - mu) * rs * g_v[fn] + b_v[fn];
        v = gelu_erf(v);
        if (outf) outf[rowg * 512 + col] = v;
        else      outb[(size_t)e * o_estride + rowg * 512 + col] = f2bf(v);
      }
    }
}

// ---------------------------------------------------------------------------
// gate GEMM2 (fp32) + softmax + top-2 + w_dense.  One wave per token.
// ---------------------------------------------------------------------------
__global__ __launch_bounds__(256) void gate2_topk(
    const float* __restrict__ gh, const float* __restrict__ w2t,
    const float* __restrict__ b2, float* __restrict__ gwout,
    float* __restrict__ idxout, float* __restrict__ tkwout,
    float* __restrict__ wdense) {
  const int lane = threadIdx.x & 63;
  const int wv = threadIdx.x >> 6;
  const int t = blockIdx.x * 4 + wv;
  const float4* xr = (const float4*)(gh + (size_t)t * 512);
  float4 x0 = xr[lane * 2], x1 = xr[lane * 2 + 1];
  float logit[8];
#pragma unroll
  for (int e = 0; e < 8; ++e) {
    const float4* wr = (const float4*)(w2t + e * 512);
    float4 w0 = wr[lane * 2], w1 = wr[lane * 2 + 1];
    float p = x0.x * w0.x + x0.y * w0.y + x0.z * w0.z + x0.w * w0.w +
              x1.x * w1.x + x1.y * w1.y + x1.z * w1.z + x1.w * w1.w;
#pragma unroll
    for (int m = 1; m < 64; m <<= 1) p += __shfl_xor(p, m, 64);
    logit[e] = p + b2[e];
  }
  if (lane == 0) {
    float mx = logit[0];
#pragma unroll
    for (int e = 1; e < 8; ++e) mx = fmaxf(mx, logit[e]);
    float w[8], ssum = 0.f;
#pragma unroll
    for (int e = 0; e < 8; ++e) { w[e] = expf(logit[e] - mx); ssum += w[e]; }
    float inv = 1.0f / ssum;
#pragma unroll
    for (int e = 0; e < 8; ++e) w[e] *= inv;
    float w1v = -1.f, w2v = -1.f; int i1 = 0, i2 = 0;
#pragma unroll
    for (int e = 0; e < 8; ++e) {
      float v = w[e];
      if (v > w1v)      { w2v = w1v; i2 = i1; w1v = v; i1 = e; }
      else if (v > w2v) { w2v = v; i2 = e; }
    }
    float s = w1v + w2v;
    float t1 = w1v / s, t2 = w2v / s;
#pragma unroll
    for (int e = 0; e < 8; ++e) gwout[t * 8 + e] = w[e];
    idxout[t * 2] = (float)i1; idxout[t * 2 + 1] = (float)i2;
    tkwout[t * 2] = t1;        tkwout[t * 2 + 1] = t2;
#pragma unroll
    for (int e = 0; e < 8; ++e)
      wdense[t * 8 + e] = (e == i1) ? t1 : ((e == i2) ? t2 : 0.0f);
  }
}

__global__ __launch_bounds__(256) void usage_k(const float* __restrict__ gw,
                                               float* __restrict__ usage) {
  __shared__ float r[256];
  int e = blockIdx.x;
  float s = 0.f;
  for (int t = threadIdx.x; t < N_TOK; t += 256) s += gw[t * 8 + e];
  r[threadIdx.x] = s;
  __syncthreads();
  for (int st = 128; st > 0; st >>= 1) {
    if (threadIdx.x < st) r[threadIdx.x] += r[threadIdx.x + st];
    __syncthreads();
  }
  if (threadIdx.x == 0) usage[e] = r[0] * (1.0f / (float)N_TOK);
}

// ---------------------------------------------------------------------------
// expert GEMM3 (h2 @ w3 + b3), weighted combine over experts, + final proj.
// ---------------------------------------------------------------------------
__global__ __launch_bounds__(256) void gemm3_proj(
    const u16* __restrict__ h, const u16* __restrict__ w3t,
    const float* __restrict__ b3, const float* __restrict__ wdense,
    const float* __restrict__ pw, const float* __restrict__ pb,
    float* __restrict__ outp) {
  __shared__ u16 As[64 * 64];
  __shared__ u16 Bs[64 * 64];
  __shared__ float combs[64 * 65];
  __shared__ float pws[64 * 65];

  const int tid = threadIdx.x;
  const int lane = tid & 63;
  const int wq = tid >> 6;
  const int l15 = lane & 15, lk = lane >> 4;
  const int rbase = blockIdx.x * 64;

  {
    int c = tid >> 2, og = (tid & 3) * 16;
#pragma unroll
    for (int i = 0; i < 16; ++i) pws[c * 65 + og + i] = pw[c * 64 + og + i];
  }

  f32x4 comb[4];
#pragma unroll
  for (int fn = 0; fn < 4; ++fn) comb[fn] = (f32x4){0.f, 0.f, 0.f, 0.f};

  for (int e = 0; e < 8; ++e) {
    f32x4 acc[4];
#pragma unroll
    for (int fn = 0; fn < 4; ++fn) acc[fn] = (f32x4){0.f, 0.f, 0.f, 0.f};
    const u16* he = h + (size_t)e * N_TOK * 512;
    const u16* we = w3t + (size_t)e * 64 * 512;
    for (int k0 = 0; k0 < 512; k0 += 64) {
      __syncthreads();
#pragma unroll
      for (int rep = 0; rep < 2; ++rep) {
        int idx = tid + rep * 256;
        int row = idx >> 3, c = idx & 7;
        bf16x8 av = *(const bf16x8*)(he + (size_t)(rbase + row) * 512 + k0 + c * 8);
        *(bf16x8*)((char*)As + SWZ(row * 128 + c * 16, row)) = av;
        bf16x8 wv = *(const bf16x8*)(we + (size_t)row * 512 + k0 + c * 8);
        *(bf16x8*)((char*)Bs + SWZ(row * 128 + c * 16, row)) = wv;
      }
      __syncthreads();
#pragma unroll
      for (int s = 0; s < 2; ++s) {
        int r = wq * 16 + l15;
        bf16x8 a = *(const bf16x8*)((char*)As + SWZ(r * 128 + s * 64 + lk * 16, r));
#pragma unroll
        for (int fn = 0; fn < 4; ++fn) {
          int n = fn * 16 + l15;
          bf16x8 b = *(const bf16x8*)((char*)Bs + SWZ(n * 128 + s * 64 + lk * 16, n));
          acc[fn] = __builtin_amdgcn_mfma_f32_16x16x32_bf16(a, b, acc[fn], 0, 0, 0);
        }
      }
    }
    float b3v[4];
#pragma unroll
    for (int fn = 0; fn < 4; ++fn) b3v[fn] = b3[e * 64 + fn * 16 + l15];
#pragma unroll
    for (int r = 0; r < 4; ++r) {
      float wgt = wdense[(size_t)(rbase + wq * 16 + lk * 4 + r) * 8 + e];
#pragma unroll
      for (int fn = 0; fn < 4; ++fn) comb[fn][r] += wgt * (acc[fn][r] + b3v[fn]);
    }
  }
#pragma unroll
  for (int fn = 0; fn < 4; ++fn)
#pragma unroll
    for (int r = 0; r < 4; ++r)
      combs[(wq * 16 + lk * 4 + r) * 65 + fn * 16 + l15] = comb[fn][r];
  __syncthreads();
  {
    int t = tid >> 2, og = (tid & 3) * 16;
    float sums[16];
#pragma unroll
    for (int i = 0; i < 16; ++i) sums[i] = 0.f;
    for (int c = 0; c < 64; ++c) {
      float cv = combs[t * 65 + c];
#pragma unroll
      for (int i = 0; i < 16; ++i) sums[i] += cv * pws[c * 65 + og + i];
    }
#pragma unroll
    for (int i = 0; i < 16; ++i)
      outp[(size_t)(rbase + t) * 64 + og + i] = sums[i] + pb[og + i];
  }
}

// ---------------------------------------------------------------------------
extern "C" void kernel_launch(void* const* d_in, const int* in_sizes, int n_in,
                              void* d_out, int out_size, void* d_ws, size_t ws_size,
                              hipStream_t stream) {
  const float* x      = (const float*)d_in[0];
  const float* g_w1   = (const float*)d_in[1];
  const float* g_b1   = (const float*)d_in[2];
  const float* g_lng  = (const float*)d_in[3];
  const float* g_lnb  = (const float*)d_in[4];
  const float* g_w2   = (const float*)d_in[5];
  const float* g_b2   = (const float*)d_in[6];
  const float* e_w1   = (const float*)d_in[7];
  const float* e_b1   = (const float*)d_in[8];
  const float* e_ln1g = (const float*)d_in[9];
  const float* e_ln1b = (const float*)d_in[10];
  const float* e_w2   = (const float*)d_in[11];
  const float* e_b2   = (const float*)d_in[12];
  const float* e_ln2g = (const float*)d_in[13];
  const float* e_ln2b = (const float*)d_in[14];
  const float* e_w3   = (const float*)d_in[15];
  const float* e_b3   = (const float*)d_in[16];
  const float* p_w    = (const float*)d_in[17];
  const float* p_b    = (const float*)d_in[18];

  char* ws = (char*)d_ws;
  u16*   x_bf  = (u16*)(ws);                     // 16 MB
  u16*   e_w1t = (u16*)(ws + (16ull << 20));     // 4 MB
  u16*   e_w2t = (u16*)(ws + (20ull << 20));     // 4 MB
  u16*   e_w3t = (u16*)(ws + (24ull << 20));     // 0.5 MB
  u16*   wcat  = (u16*)(ws + (25ull << 20));     // 1.5 MB
  float* w2t   = (float*)(ws + (27ull << 20));   // 16 KB
  float* wdns  = (float*)(ws + (28ull << 20));   // 512 KB
  float* gh    = (float*)(ws + (29ull << 20));   // 32 MB (overlaid by h later)
  u16*   x_lo  = (u16*)(ws + (61ull << 20));     // 16 MB
  u16*   h     = (u16*)(ws + (29ull << 20));     // 128 MB
  if (ws_size < (157ull << 20)) return;

  float* fout = (float*)d_out;
  float* o_output = fout;                 // 16384*64
  float* o_gatew  = fout + 1048576;       // 16384*8
  float* o_idx    = fout + 1179648;       // 16384*2
  float* o_topw   = fout + 1212416;       // 16384*2
  float* o_usage  = fout + 1245184;       // 8

  (void)hipFuncSetAttribute((const void*)gemm_ln_gelu,
                            hipFuncAttributeMaxDynamicSharedMemorySize, 81920);

  prep_x<<<8192, 256, 0, stream>>>(x, x_bf, x_lo);
  transpose_bf_tiled<<<dim3(8, 8, 8), 256, 0, stream>>>(e_w1, e_w1t, 512, 512);
  transpose_bf_tiled<<<dim3(8, 8, 8), 256, 0, stream>>>(e_w2, e_w2t, 512, 512);
  transpose_bf_tiled<<<dim3(8, 1, 8), 256, 0, stream>>>(e_w3, e_w3t, 512, 64);
  prep_wcat<<<3072, 256, 0, stream>>>(g_w1, wcat);
  prep_w2t<<<16, 256, 0, stream>>>(g_w2, w2t);

  // gate GEMM (split-bf16, K=1536, fp32-accurate) -> gh (fp32)
  gemm_ln_gelu<<<dim3(128, 1), 1024, 81920, stream>>>(
      x_bf, x_lo, 0, wcat, 0, g_b1, 0, g_lng, g_lnb, nullptr, gh, 0, 1536);
  gate2_topk<<<4096, 256, 0, stream>>>(gh, w2t, g_b2, o_gatew, o_idx, o_topw, wdns);
  usage_k<<<8, 256, 0, stream>>>(o_gatew, o_usage);

  // experts: L1 (x -> h), L2 (h -> h, in-place safe: wg reads only its own rows)
  gemm_ln_gelu<<<dim3(128, 8), 1024, 81920, stream>>>(
      x_bf, nullptr, 0, e_w1t, 512 * 512, e_b1, 512, e_ln1g, e_ln1b, h, nullptr,
      (long)N_TOK * 512, 512);
  gemm_ln_gelu<<<dim3(128, 8), 1024, 81920, stream>>>(
      h, nullptr, (long)N_TOK * 512, e_w2t, 512 * 512, e_b2, 512, e_ln2g, e_ln2b,
      h, nullptr, (long)N_TOK * 512, 512);
  gemm3_proj<<<256, 256, 0, stream>>>(h, e_w3t, e_b3, wdns, p_w, p_b, o_output);
}